// Round 7
// baseline (326.923 us; speedup 1.0000x reference)
//
#include <hip/hip_runtime.h>
#include <hip/hip_bf16.h>
#include <math.h>

// SurfaceAbstraction: gather(32 nbrs) -> 73-dim -> 3x(1x1 conv + batch BN +
// relu) -> maxpool. BN stats => 3 passes. Tiers by ws_size:
//  cached tier: cache RAW y0 (bf16 fragment layout), ONE gather total.
//    S0: gather+conv0+stats0+store y0 (NON-TEMPORAL: keeps fb table L2-hot).
//    S1: load y0->BN0->conv1->stats1.
//    S2: load y0->BN0->conv1(recompute)->BN1->conv2->stats2+pool.
//  featbf tier: bf16 feature table (4MB, L2-resident/XCD).
//  else: R5 recompute fallback.
// R7 change: y0 stores are __builtin_nontemporal_store (R6 showed the y0
// write stream thrashing per-XCD L2: stage0 FETCH 95->413MB).

typedef __attribute__((ext_vector_type(8))) short short8;
typedef __attribute__((ext_vector_type(4))) float f32x4;

constexpr int NS = 32;
constexpr int GRID0  = 1024;
constexpr int GRID12 = 768;    // fallback stage1/2 (48KB LDS)
constexpr int GRIDC  = 1024;   // cached stage1/2
constexpr float BN_EPS = 1e-5f;
constexpr float INV_PI  = 0.31830988618379067f;
constexpr float INV_2PI = 0.15915494309189535f;

__device__ __forceinline__ short cvt_bf16(float f) {
    unsigned u = __float_as_uint(f);
    u = (u + 0x7FFFu + ((u >> 16) & 1u)) >> 16;
    return (short)u;
}
__device__ __forceinline__ float bf16_to_f(short s) {
    return __uint_as_float(((unsigned)(unsigned short)s) << 16);
}
__device__ __forceinline__ unsigned pack_bf16(float lo, float hi) {
    return (unsigned)(unsigned short)cvt_bf16(lo)
         | ((unsigned)(unsigned short)cvt_bf16(hi) << 16);
}

// feature (fp32) -> bf16 table
__global__ __launch_bounds__(256) void feat2bf(
    const float* __restrict__ feature, short* __restrict__ fb, int n8)
{
    int i = blockIdx.x * 256 + threadIdx.x;
    if (i >= n8) return;
    const float4* src = (const float4*)(feature + (size_t)i * 8);
    float4 a = src[0], b = src[1];
    short8 v;
    v[0]=cvt_bf16(a.x); v[1]=cvt_bf16(a.y); v[2]=cvt_bf16(a.z); v[3]=cvt_bf16(a.w);
    v[4]=cvt_bf16(b.x); v[5]=cvt_bf16(b.y); v[6]=cvt_bf16(b.z); v[7]=cvt_bf16(b.w);
    *(short8*)(fb + (size_t)i * 8) = v;
}

// Weight fragments: frag(kt,nt), lane l holds W[n=nt*16+(l&15)][k=kt*32+(l>>4)*8+j]
// hi/lo bf16 split. conv0 K permuted: knew<64 -> orig 9+knew; 64..71 -> 0..7;
// 72 -> 8; 73..95 -> zero.
__global__ __launch_bounds__(256) void prep_weights(
    const float* __restrict__ w0, const float* __restrict__ w1,
    const float* __restrict__ w2,
    short* __restrict__ wf0h, short* __restrict__ wf0l,
    short* __restrict__ wf1h, short* __restrict__ wf1l,
    short* __restrict__ wf2h, short* __restrict__ wf2l)
{
    int i = blockIdx.x * 256 + threadIdx.x;
    int l = i & 63;
    int f = i >> 6;
    float vals[8];
    short *dh, *dl;
    if (f < 12) {
        int kt = f >> 2, nt = f & 3;
        int n = nt * 16 + (l & 15);
        int k0 = kt * 32 + (l >> 4) * 8;
        for (int j = 0; j < 8; ++j) {
            int kn = k0 + j;
            float v;
            if (kn < 64)       v = w0[n * 73 + 9 + kn];
            else if (kn < 72)  v = w0[n * 73 + (kn - 64)];
            else if (kn == 72) v = w0[n * 73 + 8];
            else v = 0.f;
            vals[j] = v;
        }
        dh = wf0h + (size_t)f * 512 + l * 8;
        dl = wf0l + (size_t)f * 512 + l * 8;
    } else if (f < 20) {
        int ff = f - 12;
        int kt = ff >> 2, nt = ff & 3;
        int n = nt * 16 + (l & 15);
        int k0 = kt * 32 + (l >> 4) * 8;
        for (int j = 0; j < 8; ++j) vals[j] = w1[n * 64 + k0 + j];
        dh = wf1h + (size_t)ff * 512 + l * 8;
        dl = wf1l + (size_t)ff * 512 + l * 8;
    } else if (f < 36) {
        int ff = f - 20;
        int kt = ff >> 3, nt = ff & 7;
        int n = nt * 16 + (l & 15);
        int k0 = kt * 32 + (l >> 4) * 8;
        for (int j = 0; j < 8; ++j) vals[j] = w2[n * 64 + k0 + j];
        dh = wf2h + (size_t)ff * 512 + l * 8;
        dl = wf2l + (size_t)ff * 512 + l * 8;
    } else return;
    for (int j = 0; j < 8; ++j) {
        short h = cvt_bf16(vals[j]);
        dh[j] = h;
        dl[j] = cvt_bf16(vals[j] - bf16_to_f(h));
    }
}

// STAGE: which layer's stats this pass produces. CACHED: y0-cache pipeline.
template <int STAGE, bool CACHED>
__global__ __launch_bounds__(256, 4) void stage_kernel(
    const float* __restrict__ center, const float* __restrict__ normal,
    const float* __restrict__ feature, const short* __restrict__ fb,
    const int* __restrict__ gidx,
    const short* __restrict__ wf0h, const short* __restrict__ wf0l,
    const short* __restrict__ wf1h, const short* __restrict__ wf1l,
    const short* __restrict__ wf2h, const short* __restrict__ wf2l,
    const float* __restrict__ b0, const float* __restrict__ b1,
    const float* __restrict__ b2,
    const float* __restrict__ g0, const float* __restrict__ be0,
    const float* __restrict__ g1, const float* __restrict__ be1,
    const float* __restrict__ fstats, float* __restrict__ part,
    float* __restrict__ ymax, float* __restrict__ ymin,
    const uint2* __restrict__ yprev, uint2* __restrict__ ynext,
    int ntiles, float inv_cnt)
{
    constexpr bool GATHER = (!CACHED) || (STAGE == 0);
    __shared__ __align__(16) short Xs[GATHER ? 128 * 128 : 16];
    __shared__ __align__(16) short X1s[(STAGE >= 1) ? 128 * 64 : 16];
    __shared__ __align__(16) short X2s[(CACHED && STAGE == 2) ? 128 * 64 : 16];

    const int t    = threadIdx.x;
    const int lane = t & 63;
    const int wv   = __builtin_amdgcn_readfirstlane(t >> 6);
    const int ln   = lane & 15;
    const int kg   = lane >> 4;
    const int rs   = ln & 7;
    const int chW  = wv * 16 + ln;      // producer channel (conv0/conv1 slices)

    // ---- weight fragments in registers ----
    short8 W0h[3], W0l[3];
    if constexpr (GATHER) {
#pragma unroll
        for (int kt = 0; kt < 3; ++kt) {
            W0h[kt] = *(const short8*)(wf0h + (size_t)((kt*4 + wv) * 64 + lane) * 8);
            W0l[kt] = *(const short8*)(wf0l + (size_t)((kt*4 + wv) * 64 + lane) * 8);
        }
    }
    short8 W1h[2], W1l[2];
    if constexpr (STAGE >= 1) {
#pragma unroll
        for (int kt = 0; kt < 2; ++kt) {
            W1h[kt] = *(const short8*)(wf1h + (size_t)((kt*4 + wv) * 64 + lane) * 8);
            W1l[kt] = *(const short8*)(wf1l + (size_t)((kt*4 + wv) * 64 + lane) * 8);
        }
    }
    short8 W2h[2][2], W2l[2][2];
    if constexpr (STAGE == 2) {
#pragma unroll
        for (int nti = 0; nti < 2; ++nti)
#pragma unroll
            for (int kt = 0; kt < 2; ++kt) {
                int ff = kt * 8 + (wv * 2 + nti);
                W2h[nti][kt] = *(const short8*)(wf2h + (size_t)(ff * 64 + lane) * 8);
                W2l[nti][kt] = *(const short8*)(wf2l + (size_t)(ff * 64 + lane) * 8);
            }
    }

    // ---- biases / BN consts ----
    float bb0 = 0.f, bb1 = 0.f, bb2a = 0.f, bb2b = 0.f;
    float a0v = 0.f, c0v = 0.f;          // BN0 producer-side (fallback S1/S2)
    float a1v = 0.f, c1v = 0.f;          // BN1 producer-side (S2 both tiers)
    float aPv = 0.f, cPv = 0.f;          // BN0 consumer-side (cached, ch=lane)
    if constexpr (GATHER) bb0 = b0[chW];
    if constexpr (STAGE >= 1) {
        bb1 = b1[chW];
        if constexpr (CACHED) {
            float mean = fstats[lane] * inv_cnt;
            float var  = fstats[64 + lane] * inv_cnt - mean * mean;
            aPv = g0[lane] * rsqrtf(fmaxf(var, 0.f) + BN_EPS);
            cPv = be0[lane] - aPv * mean;
        } else {
            float mean = fstats[chW] * inv_cnt;
            float var  = fstats[64 + chW] * inv_cnt - mean * mean;
            a0v = g0[chW] * rsqrtf(fmaxf(var, 0.f) + BN_EPS);
            c0v = be0[chW] - a0v * mean;
        }
    }
    if constexpr (STAGE == 2) {
        bb2a = b2[wv * 32 + ln];
        bb2b = b2[wv * 32 + 16 + ln];
        float mean = fstats[128 + chW] * inv_cnt;
        float var  = fstats[192 + chW] * inv_cnt - mean * mean;
        a1v = g1[chW] * rsqrtf(fmaxf(var, 0.f) + BN_EPS);
        c1v = be1[chW] - a1v * mean;
    }

    if constexpr (GATHER) {   // zero pad units 10,11 (k 80..95) once
        int r = t >> 1, u = 10 + (t & 1);
        short8 z; z[0]=0;z[1]=0;z[2]=0;z[3]=0;z[4]=0;z[5]=0;z[6]=0;z[7]=0;
        *(short8*)(Xs + r * 128 + ((u ^ (r & 7)) * 8)) = z;
    }

    constexpr int NT = (STAGE == 2) ? 2 : 1;
    float ssum[NT], ssq[NT];
#pragma unroll
    for (int nt = 0; nt < NT; ++nt) { ssum[nt] = 0.f; ssq[nt] = 0.f; }

    for (int tile = blockIdx.x; tile < ntiles; tile += gridDim.x) {
        const int m0 = tile * 4;
        __syncthreads();                    // prior tile's LDS reads done

        if constexpr (GATHER) {
            // ---- gather: 128 samples, 2 threads/sample ----
            const int s = t & 127, h = t >> 7;
            const int m = m0 + (s >> 5);
            const int j = gidx[m * NS + (s & 31)];
            short* xr = Xs + s * 128;
            const int rx = (s & 7) * 8;
            if (fb) {                       // bf16 table: straight 16B copies
                const uint4* fp = (const uint4*)(fb + (size_t)j * 64);
#pragma unroll
                for (int q = 0; q < 4; ++q) {
                    uint4 v = fp[h * 4 + q];
                    *(uint4*)(xr + ((((h * 4 + q) * 8)) ^ rx)) = v;
                }
            } else {
                const float4* fp = (const float4*)(feature + (size_t)j * 64 + h * 32);
#pragma unroll
                for (int q = 0; q < 4; ++q) {
                    float4 a = fp[2 * q], b = fp[2 * q + 1];
                    short8 v;
                    v[0]=cvt_bf16(a.x); v[1]=cvt_bf16(a.y); v[2]=cvt_bf16(a.z); v[3]=cvt_bf16(a.w);
                    v[4]=cvt_bf16(b.x); v[5]=cvt_bf16(b.y); v[6]=cvt_bf16(b.z); v[7]=cvt_bf16(b.w);
                    *(short8*)(xr + ((((h * 4 + q) * 8)) ^ rx)) = v;
                }
            }
            if (h == 0) {
                float gx = center[j*3+0] - center[m*3+0];
                float gy = center[j*3+1] - center[m*3+1];
                float gz = center[j*3+2] - center[m*3+2];
                float rho = sqrtf(gx*gx + gy*gy + gz*gz);
                float th = 0.f;
                if (rho > 0.f) th = acosf(fminf(1.f, fmaxf(-1.f, gz / rho))) * INV_PI;
                float ph = atan2f(gy, gx) * INV_2PI + 0.5f;
                short8 v;
                v[0]=cvt_bf16(gx);  v[1]=cvt_bf16(gy); v[2]=cvt_bf16(gz);
                v[3]=cvt_bf16(rho); v[4]=cvt_bf16(th); v[5]=cvt_bf16(ph);
                v[6]=cvt_bf16(normal[j*3+0]); v[7]=cvt_bf16(normal[j*3+1]);
                *(short8*)(xr + ((8 * 8) ^ rx)) = v;
            } else {
                short8 v; v[0]=cvt_bf16(normal[j*3+2]);
                v[1]=0;v[2]=0;v[3]=0;v[4]=0;v[5]=0;v[6]=0;v[7]=0;
                *(short8*)(xr + ((9 * 8) ^ rx)) = v;
            }
            __syncthreads();
            // ---- conv0: K=96 ----
#pragma unroll 2
            for (int mt = 0; mt < 8; ++mt) {
                const short* arow = Xs + (mt * 16 + ln) * 128;
                f32x4 acc = {bb0, bb0, bb0, bb0};
#pragma unroll
                for (int kt = 0; kt < 3; ++kt) {
                    short8 A = *(const short8*)(arow + (((kt*4 + kg) ^ rs) * 8));
                    acc = __builtin_amdgcn_mfma_f32_16x16x32_bf16(A, W0h[kt], acc, 0, 0, 0);
                    acc = __builtin_amdgcn_mfma_f32_16x16x32_bf16(A, W0l[kt], acc, 0, 0, 0);
                }
                if constexpr (STAGE == 0) {
#pragma unroll
                    for (int r = 0; r < 4; ++r) { float y = acc[r]; ssum[0] += y; ssq[0] += y*y; }
                    if constexpr (CACHED) {     // store raw y0 fragment (non-temporal:
                        // write-once stream; keep fb table L2-resident)
                        unsigned long long d64 =
                            (unsigned long long)pack_bf16(acc[0], acc[1])
                          | ((unsigned long long)pack_bf16(acc[2], acc[3]) << 32);
                        __builtin_nontemporal_store(d64,
                            (unsigned long long*)&ynext[(size_t)tile * 2048 + mt * 256 + wv * 64 + kg * 16 + ln]);
                    }
                } else {                        // fallback S1/S2: X1 to LDS
#pragma unroll
                    for (int r = 0; r < 4; ++r) {
                        int row = mt * 16 + kg * 4 + r;
                        float x1 = fmaxf(a0v * acc[r] + c0v, 0.f);
                        X1s[row * 64 + ((((chW >> 3) ^ (row & 7)) << 3) | (chW & 7))] = cvt_bf16(x1);
                    }
                }
            }
        }

        if constexpr (CACHED && STAGE >= 1) {
            // ---- consumer: load y0 fragments (ch = lane), BN0+relu -> X1s ----
            const uint2* yb = yprev + (size_t)tile * 2048;
#pragma unroll
            for (int mi = 0; mi < 2; ++mi) {
                const int mt = wv * 2 + mi;
                uint2 v[4];
#pragma unroll
                for (int k2 = 0; k2 < 4; ++k2)
                    v[k2] = yb[mt * 256 + (lane >> 4) * 64 + k2 * 16 + (lane & 15)];
#pragma unroll
                for (int k2 = 0; k2 < 4; ++k2) {
#pragma unroll
                    for (int rp = 0; rp < 2; ++rp) {
                        unsigned d = rp ? v[k2].y : v[k2].x;
                        float flo = __uint_as_float(d << 16);
                        float fhi = __uint_as_float(d & 0xFFFF0000u);
                        int row0 = mt * 16 + k2 * 4 + rp * 2;
                        float x0  = fmaxf(aPv * flo + cPv, 0.f);
                        float x1v = fmaxf(aPv * fhi + cPv, 0.f);
                        X1s[row0 * 64 + ((((lane >> 3) ^ (row0 & 7)) << 3) | (lane & 7))] = cvt_bf16(x0);
                        int row1 = row0 + 1;
                        X1s[row1 * 64 + ((((lane >> 3) ^ (row1 & 7)) << 3) | (lane & 7))] = cvt_bf16(x1v);
                    }
                }
            }
        }

        if constexpr (STAGE >= 1) {
            __syncthreads();               // X1s complete
            // ---- conv1: K=64 from X1s ----
#pragma unroll 2
            for (int mt = 0; mt < 8; ++mt) {
                const short* arow = X1s + (mt * 16 + ln) * 64;
                f32x4 acc = {bb1, bb1, bb1, bb1};
#pragma unroll
                for (int kt = 0; kt < 2; ++kt) {
                    short8 A = *(const short8*)(arow + (((kt*4 + kg) ^ rs) * 8));
                    acc = __builtin_amdgcn_mfma_f32_16x16x32_bf16(A, W1h[kt], acc, 0, 0, 0);
                    acc = __builtin_amdgcn_mfma_f32_16x16x32_bf16(A, W1l[kt], acc, 0, 0, 0);
                }
                if constexpr (STAGE == 1) {
#pragma unroll
                    for (int r = 0; r < 4; ++r) { float y = acc[r]; ssum[0] += y; ssq[0] += y*y; }
                } else {                    // S2: X2 image (cached->X2s, fallback->Xs)
#pragma unroll
                    for (int r = 0; r < 4; ++r) {
                        int row = mt * 16 + kg * 4 + r;
                        float x2 = fmaxf(a1v * acc[r] + c1v, 0.f);
                        short val = cvt_bf16(x2);
                        if constexpr (CACHED)
                            X2s[row * 64 + ((((chW >> 3) ^ (row & 7)) << 3) | (chW & 7))] = val;
                        else
                            Xs[row * 128 + ((((chW >> 3) ^ (row & 7)) << 3) | (chW & 7))] = val;
                    }
                }
            }
        }

        if constexpr (STAGE == 2) {
            __syncthreads();               // X2 complete
            const short* img = CACHED ? X2s : Xs;
            const int istride = CACHED ? 64 : 128;
            // ---- conv2 + stats + max/min ----
#pragma unroll
            for (int p = 0; p < 4; ++p) {
                float mx0 = -3.402823466e38f, mn0 = 3.402823466e38f;
                float mx1 = -3.402823466e38f, mn1 = 3.402823466e38f;
#pragma unroll
                for (int mh = 0; mh < 2; ++mh) {
                    const int mt = p * 2 + mh;
                    const short* arow = img + (mt * 16 + ln) * istride;
                    short8 A0 = *(const short8*)(arow + (((kg)     ^ rs) * 8));
                    short8 A1 = *(const short8*)(arow + (((4 + kg) ^ rs) * 8));
                    f32x4 acc = {bb2a, bb2a, bb2a, bb2a};
                    acc = __builtin_amdgcn_mfma_f32_16x16x32_bf16(A0, W2h[0][0], acc, 0, 0, 0);
                    acc = __builtin_amdgcn_mfma_f32_16x16x32_bf16(A0, W2l[0][0], acc, 0, 0, 0);
                    acc = __builtin_amdgcn_mfma_f32_16x16x32_bf16(A1, W2h[0][1], acc, 0, 0, 0);
                    acc = __builtin_amdgcn_mfma_f32_16x16x32_bf16(A1, W2l[0][1], acc, 0, 0, 0);
#pragma unroll
                    for (int r = 0; r < 4; ++r) {
                        float y = acc[r];
                        ssum[0] += y; ssq[0] += y * y;
                        mx0 = fmaxf(mx0, y); mn0 = fminf(mn0, y);
                    }
                    f32x4 acd = {bb2b, bb2b, bb2b, bb2b};
                    acd = __builtin_amdgcn_mfma_f32_16x16x32_bf16(A0, W2h[1][0], acd, 0, 0, 0);
                    acd = __builtin_amdgcn_mfma_f32_16x16x32_bf16(A0, W2l[1][0], acd, 0, 0, 0);
                    acd = __builtin_amdgcn_mfma_f32_16x16x32_bf16(A1, W2h[1][1], acd, 0, 0, 0);
                    acd = __builtin_amdgcn_mfma_f32_16x16x32_bf16(A1, W2l[1][1], acd, 0, 0, 0);
#pragma unroll
                    for (int r = 0; r < 4; ++r) {
                        float y = acd[r];
                        ssum[1] += y; ssq[1] += y * y;
                        mx1 = fmaxf(mx1, y); mn1 = fminf(mn1, y);
                    }
                }
                mx0 = fmaxf(mx0, __shfl_xor(mx0, 16)); mn0 = fminf(mn0, __shfl_xor(mn0, 16));
                mx0 = fmaxf(mx0, __shfl_xor(mx0, 32)); mn0 = fminf(mn0, __shfl_xor(mn0, 32));
                mx1 = fmaxf(mx1, __shfl_xor(mx1, 16)); mn1 = fminf(mn1, __shfl_xor(mn1, 16));
                mx1 = fmaxf(mx1, __shfl_xor(mx1, 32)); mn1 = fminf(mn1, __shfl_xor(mn1, 32));
                if (lane < 16) {
                    size_t base = (size_t)(m0 + p) * 128 + wv * 32 + ln;
                    ymax[base]      = mx0; ymin[base]      = mn0;
                    ymax[base + 16] = mx1; ymin[base + 16] = mn1;
                }
            }
        }
    }

    // ---- stats epilogue ----
    float* pb = part + (size_t)blockIdx.x * 256;
#pragma unroll
    for (int nt = 0; nt < NT; ++nt) {
        float v = ssum[nt], q = ssq[nt];
        v += __shfl_xor(v, 16); q += __shfl_xor(q, 16);
        v += __shfl_xor(v, 32); q += __shfl_xor(q, 32);
        if (lane < 16) {
            constexpr int NCH = (STAGE == 2) ? 128 : 64;
            int c = (STAGE == 2) ? (wv * 32 + nt * 16 + ln) : (wv * 16 + ln);
            pb[c] = v; pb[NCH + c] = q;
        }
    }
}

__global__ __launch_bounds__(256) void reduce_partials(
    const float* __restrict__ part, float* __restrict__ fstats,
    int base, int nblocks)
{
    __shared__ float red[256];
    int c = blockIdx.x;
    float s = 0.f;
    for (int b = threadIdx.x; b < nblocks; b += 256)
        s += part[(size_t)b * 256 + c];
    red[threadIdx.x] = s;
    __syncthreads();
    for (int off = 128; off > 0; off >>= 1) {
        if (threadIdx.x < off) red[threadIdx.x] += red[threadIdx.x + off];
        __syncthreads();
    }
    if (threadIdx.x == 0) fstats[base + c] = red[0];
}

__global__ __launch_bounds__(256) void final_kernel(
    const float* __restrict__ center, const float* __restrict__ normal,
    const int* __restrict__ offs,
    const float* __restrict__ g2, const float* __restrict__ be2,
    const float* __restrict__ fstats,
    const float* __restrict__ ymax, const float* __restrict__ ymin,
    float* __restrict__ out, int N, float inv_cnt)
{
    int i = blockIdx.x * 256 + threadIdx.x;
    int nc = N * 3;
    int nf = N * 128;
    int total = 2 * nc + nf + 1;
    if (i >= total) return;
    if (i < nc) {
        out[i] = center[i];
    } else if (i < 2 * nc) {
        out[i] = normal[i - nc];
    } else if (i < 2 * nc + nf) {
        int idx = i - 2 * nc;
        int c = idx & 127;
        float mean = fstats[256 + c] * inv_cnt;
        float var  = fstats[384 + c] * inv_cnt - mean * mean;
        float a = g2[c] * rsqrtf(fmaxf(var, 0.f) + BN_EPS);
        float v = (a >= 0.f) ? ymax[idx] : ymin[idx];
        out[i] = fmaxf(a * (v - mean) + be2[c], 0.f);
    } else {
        out[i] = (float)offs[0];
    }
}

extern "C" void kernel_launch(void* const* d_in, const int* in_sizes, int n_in,
                              void* d_out, int out_size, void* d_ws, size_t ws_size,
                              hipStream_t stream)
{
    const float* center  = (const float*)d_in[0];
    const float* normal  = (const float*)d_in[1];
    const float* feature = (const float*)d_in[2];
    const int*   offs    = (const int*)d_in[3];
    const int*   gidx    = (const int*)d_in[4];
    const float* w0  = (const float*)d_in[5];
    const float* b0  = (const float*)d_in[6];
    const float* g0  = (const float*)d_in[7];
    const float* be0 = (const float*)d_in[8];
    const float* w1  = (const float*)d_in[9];
    const float* b1  = (const float*)d_in[10];
    const float* g1  = (const float*)d_in[11];
    const float* be1 = (const float*)d_in[12];
    const float* w2  = (const float*)d_in[13];
    const float* b2  = (const float*)d_in[14];
    const float* g2  = (const float*)d_in[15];
    const float* be2 = (const float*)d_in[16];

    const int N = in_sizes[0] / 3;
    const int ntiles = N / 4;
    const float inv_cnt = 1.0f / (float)((size_t)N * NS);

    float* out = (float*)d_out;
    float* out_nf = out + (size_t)2 * N * 3;          // ymax in-place in d_out

    float* wsf    = (float*)d_ws;
    float* fstats = wsf;                              // [512]
    float* part   = wsf + 512;                        // [1024*256]
    float* ymin   = part + (size_t)1024 * 256;        // [N*128]
    short* wbase  = (short*)(ymin + (size_t)N * 128);
    short* wf0h = wbase;
    short* wf0l = wf0h + 12 * 512;
    short* wf1h = wf0l + 12 * 512;
    short* wf1l = wf1h + 8 * 512;
    short* wf2h = wf1l + 8 * 512;
    short* wf2l = wf2h + 16 * 512;
    short* wend = wf2l + 16 * 512;

    // tier boundaries
    short* featbf = wend;                             // [N*64] bf16 table
    size_t need_fb = (size_t)((char*)(featbf + (size_t)N * 64) - (char*)d_ws);
    uint2* y0 = (uint2*)(featbf + (size_t)N * 64);    // [ntiles*2048] uint2
    size_t need_cached = need_fb + (size_t)ntiles * 2048 * sizeof(uint2);

    const bool has_fb = (ws_size >= need_fb);
    const bool cached = (ws_size >= need_cached);
    const short* fbp = has_fb ? featbf : nullptr;

    dim3 blk(256);

    prep_weights<<<dim3(9), blk, 0, stream>>>(w0, w1, w2,
        wf0h, wf0l, wf1h, wf1l, wf2h, wf2l);
    if (has_fb) {
        int n8 = N * 8;                               // N*64/8 vectors
        feat2bf<<<dim3((n8 + 255) / 256), blk, 0, stream>>>(feature, featbf, n8);
    }

    if (cached) {
        stage_kernel<0, true><<<dim3(GRID0), blk, 0, stream>>>(center, normal, feature, fbp, gidx,
            wf0h, wf0l, wf1h, wf1l, wf2h, wf2l, b0, b1, b2,
            g0, be0, g1, be1, fstats, part, out_nf, ymin, nullptr, y0, ntiles, inv_cnt);
        reduce_partials<<<dim3(128), blk, 0, stream>>>(part, fstats, 0, GRID0);

        stage_kernel<1, true><<<dim3(GRIDC), blk, 0, stream>>>(center, normal, feature, fbp, gidx,
            wf0h, wf0l, wf1h, wf1l, wf2h, wf2l, b0, b1, b2,
            g0, be0, g1, be1, fstats, part, out_nf, ymin, y0, nullptr, ntiles, inv_cnt);
        reduce_partials<<<dim3(128), blk, 0, stream>>>(part, fstats, 128, GRIDC);

        stage_kernel<2, true><<<dim3(GRIDC), blk, 0, stream>>>(center, normal, feature, fbp, gidx,
            wf0h, wf0l, wf1h, wf1l, wf2h, wf2l, b0, b1, b2,
            g0, be0, g1, be1, fstats, part, out_nf, ymin, y0, nullptr, ntiles, inv_cnt);
        reduce_partials<<<dim3(256), blk, 0, stream>>>(part, fstats, 256, GRIDC);
    } else {
        stage_kernel<0, false><<<dim3(GRID0), blk, 0, stream>>>(center, normal, feature, fbp, gidx,
            wf0h, wf0l, wf1h, wf1l, wf2h, wf2l, b0, b1, b2,
            g0, be0, g1, be1, fstats, part, out_nf, ymin, nullptr, nullptr, ntiles, inv_cnt);
        reduce_partials<<<dim3(128), blk, 0, stream>>>(part, fstats, 0, GRID0);

        stage_kernel<1, false><<<dim3(GRID12), blk, 0, stream>>>(center, normal, feature, fbp, gidx,
            wf0h, wf0l, wf1h, wf1l, wf2h, wf2l, b0, b1, b2,
            g0, be0, g1, be1, fstats, part, out_nf, ymin, nullptr, nullptr, ntiles, inv_cnt);
        reduce_partials<<<dim3(128), blk, 0, stream>>>(part, fstats, 128, GRID12);

        stage_kernel<2, false><<<dim3(GRID12), blk, 0, stream>>>(center, normal, feature, fbp, gidx,
            wf0h, wf0l, wf1h, wf1l, wf2h, wf2l, b0, b1, b2,
            g0, be0, g1, be1, fstats, part, out_nf, ymin, nullptr, nullptr, ntiles, inv_cnt);
        reduce_partials<<<dim3(256), blk, 0, stream>>>(part, fstats, 256, GRID12);
    }

    int total = 2 * N * 3 + N * 128 + 1;
    final_kernel<<<dim3((total + 255) / 256), blk, 0, stream>>>(
        center, normal, offs, g2, be2, fstats, out_nf, ymin, out, N, inv_cnt);
}

// Round 8
// 248.696 us; speedup vs baseline: 1.3146x; 1.3146x over previous
//
#include <hip/hip_runtime.h>
#include <hip/hip_bf16.h>
#include <math.h>

// SurfaceAbstraction: gather(32 nbrs) -> 73-dim -> 3x(1x1 conv + batch BN +
// relu) -> maxpool. BN stats => 3 recompute passes (R4 structure: best wall;
// y0-cache writes polluted L2 and lost, R6/R7 evidence).
// R8: cut gather traffic: (1) bf16 feature table (4MB: half the random bytes,
// zero cvt in the hot loop); (2) packed cn table [cx,cy,cz,nx|ny,nz,0,0] fp32
// (one aligned 16B read per half-sample instead of 2-3 scattered 12B reads).
// Channel map: knew<64=feat; 64..69=gx,gy,gz,rho,th,ph; 70=nx; 72=ny; 73=nz.

typedef __attribute__((ext_vector_type(8))) short short8;
typedef __attribute__((ext_vector_type(4))) float f32x4;

constexpr int NS = 32;
constexpr int GRID0  = 1024;   // S0: 32KB LDS -> 4/CU
constexpr int GRID12 = 768;    // S1/S2: 48KB LDS -> 3/CU
constexpr float BN_EPS = 1e-5f;
constexpr float INV_PI  = 0.31830988618379067f;
constexpr float INV_2PI = 0.15915494309189535f;

__device__ __forceinline__ short cvt_bf16(float f) {
    unsigned u = __float_as_uint(f);
    u = (u + 0x7FFFu + ((u >> 16) & 1u)) >> 16;
    return (short)u;
}
__device__ __forceinline__ float bf16_to_f(short s) {
    return __uint_as_float(((unsigned)(unsigned short)s) << 16);
}

// feature (fp32) -> bf16 table
__global__ __launch_bounds__(256) void feat2bf(
    const float* __restrict__ feature, short* __restrict__ fb, int n8)
{
    int i = blockIdx.x * 256 + threadIdx.x;
    if (i >= n8) return;
    const float4* src = (const float4*)(feature + (size_t)i * 8);
    float4 a = src[0], b = src[1];
    short8 v;
    v[0]=cvt_bf16(a.x); v[1]=cvt_bf16(a.y); v[2]=cvt_bf16(a.z); v[3]=cvt_bf16(a.w);
    v[4]=cvt_bf16(b.x); v[5]=cvt_bf16(b.y); v[6]=cvt_bf16(b.z); v[7]=cvt_bf16(b.w);
    *(short8*)(fb + (size_t)i * 8) = v;
}

// packed per-point table: [cx,cy,cz,nx | ny,nz,0,0] fp32
__global__ __launch_bounds__(256) void prep_cn(
    const float* __restrict__ center, const float* __restrict__ normal,
    float* __restrict__ cn, int N)
{
    int i = blockIdx.x * 256 + threadIdx.x;
    if (i >= N) return;
    float4 a, b;
    a.x = center[i*3+0]; a.y = center[i*3+1]; a.z = center[i*3+2];
    a.w = normal[i*3+0];
    b.x = normal[i*3+1]; b.y = normal[i*3+2]; b.z = 0.f; b.w = 0.f;
    *(float4*)(cn + (size_t)i * 8)     = a;
    *(float4*)(cn + (size_t)i * 8 + 4) = b;
}

// Weight fragments: frag(kt,nt), lane l holds W[n=nt*16+(l&15)][k=kt*32+(l>>4)*8+j]
// hi/lo bf16 split. conv0 K map: kn<64 -> orig 9+kn (feat); 64..69 -> orig
// 0..5 (gcn6); 70 -> orig 6 (nx); 72 -> orig 7 (ny); 73 -> orig 8 (nz);
// 71, 74..95 -> zero.
__global__ __launch_bounds__(256) void prep_weights(
    const float* __restrict__ w0, const float* __restrict__ w1,
    const float* __restrict__ w2,
    short* __restrict__ wf0h, short* __restrict__ wf0l,
    short* __restrict__ wf1h, short* __restrict__ wf1l,
    short* __restrict__ wf2h, short* __restrict__ wf2l)
{
    int i = blockIdx.x * 256 + threadIdx.x;
    int l = i & 63;
    int f = i >> 6;
    float vals[8];
    short *dh, *dl;
    if (f < 12) {
        int kt = f >> 2, nt = f & 3;
        int n = nt * 16 + (l & 15);
        int k0 = kt * 32 + (l >> 4) * 8;
        for (int j = 0; j < 8; ++j) {
            int kn = k0 + j;
            float v;
            if (kn < 64)       v = w0[n * 73 + 9 + kn];
            else if (kn < 70)  v = w0[n * 73 + (kn - 64)];
            else if (kn == 70) v = w0[n * 73 + 6];
            else if (kn == 72) v = w0[n * 73 + 7];
            else if (kn == 73) v = w0[n * 73 + 8];
            else v = 0.f;
            vals[j] = v;
        }
        dh = wf0h + (size_t)f * 512 + l * 8;
        dl = wf0l + (size_t)f * 512 + l * 8;
    } else if (f < 20) {
        int ff = f - 12;
        int kt = ff >> 2, nt = ff & 3;
        int n = nt * 16 + (l & 15);
        int k0 = kt * 32 + (l >> 4) * 8;
        for (int j = 0; j < 8; ++j) vals[j] = w1[n * 64 + k0 + j];
        dh = wf1h + (size_t)ff * 512 + l * 8;
        dl = wf1l + (size_t)ff * 512 + l * 8;
    } else if (f < 36) {
        int ff = f - 20;
        int kt = ff >> 3, nt = ff & 7;
        int n = nt * 16 + (l & 15);
        int k0 = kt * 32 + (l >> 4) * 8;
        for (int j = 0; j < 8; ++j) vals[j] = w2[n * 64 + k0 + j];
        dh = wf2h + (size_t)ff * 512 + l * 8;
        dl = wf2l + (size_t)ff * 512 + l * 8;
    } else return;
    for (int j = 0; j < 8; ++j) {
        short h = cvt_bf16(vals[j]);
        dh[j] = h;
        dl[j] = cvt_bf16(vals[j] - bf16_to_f(h));
    }
}

template <int STAGE>
__global__ __launch_bounds__(256, 4) void stage_kernel(
    const float* __restrict__ center, const float* __restrict__ normal,
    const float* __restrict__ feature, const short* __restrict__ fb,
    const float* __restrict__ cn, const int* __restrict__ gidx,
    const short* __restrict__ wf0h, const short* __restrict__ wf0l,
    const short* __restrict__ wf1h, const short* __restrict__ wf1l,
    const short* __restrict__ wf2h, const short* __restrict__ wf2l,
    const float* __restrict__ b0, const float* __restrict__ b1,
    const float* __restrict__ b2,
    const float* __restrict__ g0, const float* __restrict__ be0,
    const float* __restrict__ g1, const float* __restrict__ be1,
    const float* __restrict__ fstats, float* __restrict__ part,
    float* __restrict__ ymax, float* __restrict__ ymin,
    int ntiles, float inv_cnt)
{
    // Xs: 128 rows x 16 units(16B), swizzle: unit u of row r at u^(r&7)
    __shared__ __align__(16) short Xs[128 * 128];
    __shared__ __align__(16) short X1s[(STAGE >= 1) ? 128 * 64 : 16];

    const int t    = threadIdx.x;
    const int lane = t & 63;
    const int wv   = __builtin_amdgcn_readfirstlane(t >> 6);
    const int ln   = lane & 15;
    const int kg   = lane >> 4;
    const int rs   = ln & 7;
    const int chW  = wv * 16 + ln;

    // ---- weight fragments in registers ----
    short8 W0h[3], W0l[3];
#pragma unroll
    for (int kt = 0; kt < 3; ++kt) {
        W0h[kt] = *(const short8*)(wf0h + (size_t)((kt*4 + wv) * 64 + lane) * 8);
        W0l[kt] = *(const short8*)(wf0l + (size_t)((kt*4 + wv) * 64 + lane) * 8);
    }
    short8 W1h[2], W1l[2];
    if constexpr (STAGE >= 1) {
#pragma unroll
        for (int kt = 0; kt < 2; ++kt) {
            W1h[kt] = *(const short8*)(wf1h + (size_t)((kt*4 + wv) * 64 + lane) * 8);
            W1l[kt] = *(const short8*)(wf1l + (size_t)((kt*4 + wv) * 64 + lane) * 8);
        }
    }
    short8 W2h[2][2], W2l[2][2];
    if constexpr (STAGE == 2) {
#pragma unroll
        for (int nti = 0; nti < 2; ++nti)
#pragma unroll
            for (int kt = 0; kt < 2; ++kt) {
                int ff = kt * 8 + (wv * 2 + nti);
                W2h[nti][kt] = *(const short8*)(wf2h + (size_t)(ff * 64 + lane) * 8);
                W2l[nti][kt] = *(const short8*)(wf2l + (size_t)(ff * 64 + lane) * 8);
            }
    }

    // ---- biases / BN consts (per-lane; channel fixed) ----
    const float bb0 = b0[chW];
    float bb1 = 0.f, bb2a = 0.f, bb2b = 0.f;
    float a0v = 0.f, c0v = 0.f, a1v = 0.f, c1v = 0.f;
    if constexpr (STAGE >= 1) {
        bb1 = b1[chW];
        float mean = fstats[chW] * inv_cnt;
        float var  = fstats[64 + chW] * inv_cnt - mean * mean;
        a0v = g0[chW] * rsqrtf(fmaxf(var, 0.f) + BN_EPS);
        c0v = be0[chW] - a0v * mean;
    }
    if constexpr (STAGE == 2) {
        bb2a = b2[wv * 32 + ln];
        bb2b = b2[wv * 32 + 16 + ln];
        float mean = fstats[128 + chW] * inv_cnt;
        float var  = fstats[192 + chW] * inv_cnt - mean * mean;
        a1v = g1[chW] * rsqrtf(fmaxf(var, 0.f) + BN_EPS);
        c1v = be1[chW] - a1v * mean;
    }

    {   // zero pad units 10,11 (k 80..95) once; never overwritten
        int r = t >> 1, u = 10 + (t & 1);
        short8 z; z[0]=0;z[1]=0;z[2]=0;z[3]=0;z[4]=0;z[5]=0;z[6]=0;z[7]=0;
        *(short8*)(Xs + r * 128 + ((u ^ (r & 7)) * 8)) = z;
    }

    constexpr int NT = (STAGE == 2) ? 2 : 1;
    float ssum[NT], ssq[NT];
#pragma unroll
    for (int nt = 0; nt < NT; ++nt) { ssum[nt] = 0.f; ssq[nt] = 0.f; }

    for (int tile = blockIdx.x; tile < ntiles; tile += gridDim.x) {
        const int m0 = tile * 4;
        __syncthreads();               // prior tile's LDS reads done
        {   // ---- gather: 128 samples, 2 threads/sample ----
            const int s = t & 127, h = t >> 7;
            const int m = m0 + (s >> 5);
            const int j = gidx[m * NS + (s & 31)];
            short* xr = Xs + s * 128;
            const int rx = (s & 7) * 8;
            if (fb) {                  // bf16 table: pure 16B copies
                const uint4* fp = (const uint4*)(fb + (size_t)j * 64);
#pragma unroll
                for (int q = 0; q < 4; ++q) {
                    uint4 v = fp[h * 4 + q];
                    *(uint4*)(xr + ((((h * 4 + q) * 8)) ^ rx)) = v;
                }
            } else {
                const float4* fp = (const float4*)(feature + (size_t)j * 64 + h * 32);
#pragma unroll
                for (int q = 0; q < 4; ++q) {
                    float4 a = fp[2 * q], b = fp[2 * q + 1];
                    short8 v;
                    v[0]=cvt_bf16(a.x); v[1]=cvt_bf16(a.y); v[2]=cvt_bf16(a.z); v[3]=cvt_bf16(a.w);
                    v[4]=cvt_bf16(b.x); v[5]=cvt_bf16(b.y); v[6]=cvt_bf16(b.z); v[7]=cvt_bf16(b.w);
                    *(short8*)(xr + ((((h * 4 + q) * 8)) ^ rx)) = v;
                }
            }
            if (h == 0) {              // unit 8: [gx,gy,gz,rho,th,ph,nx,0]
                float cjx, cjy, cjz, nx, cmx, cmy, cmz;
                if (cn) {
                    float4 cj = *(const float4*)(cn + (size_t)j * 8);
                    float4 cm = *(const float4*)(cn + (size_t)m * 8);
                    cjx=cj.x; cjy=cj.y; cjz=cj.z; nx=cj.w;
                    cmx=cm.x; cmy=cm.y; cmz=cm.z;
                } else {
                    cjx=center[j*3+0]; cjy=center[j*3+1]; cjz=center[j*3+2];
                    nx=normal[j*3+0];
                    cmx=center[m*3+0]; cmy=center[m*3+1]; cmz=center[m*3+2];
                }
                float gx = cjx - cmx, gy = cjy - cmy, gz = cjz - cmz;
                float rho = sqrtf(gx*gx + gy*gy + gz*gz);
                float th = 0.f;
                if (rho > 0.f) th = acosf(fminf(1.f, fmaxf(-1.f, gz / rho))) * INV_PI;
                float ph = atan2f(gy, gx) * INV_2PI + 0.5f;
                short8 v;
                v[0]=cvt_bf16(gx);  v[1]=cvt_bf16(gy); v[2]=cvt_bf16(gz);
                v[3]=cvt_bf16(rho); v[4]=cvt_bf16(th); v[5]=cvt_bf16(ph);
                v[6]=cvt_bf16(nx);  v[7]=0;
                *(short8*)(xr + ((8 * 8) ^ rx)) = v;
            } else {                   // unit 9: [ny,nz,0,...]
                float ny, nz;
                if (cn) {
                    float4 w = *(const float4*)(cn + (size_t)j * 8 + 4);
                    ny = w.x; nz = w.y;
                } else {
                    ny = normal[j*3+1]; nz = normal[j*3+2];
                }
                short8 v; v[0]=cvt_bf16(ny); v[1]=cvt_bf16(nz);
                v[2]=0;v[3]=0;v[4]=0;v[5]=0;v[6]=0;v[7]=0;
                *(short8*)(xr + ((9 * 8) ^ rx)) = v;
            }
        }
        __syncthreads();
        // ---- conv0: wave's 16 cols x all 8 m-tiles, K=96 ----
#pragma unroll 2
        for (int mt = 0; mt < 8; ++mt) {
            const short* arow = Xs + (mt * 16 + ln) * 128;
            f32x4 acc = {bb0, bb0, bb0, bb0};
#pragma unroll
            for (int kt = 0; kt < 3; ++kt) {
                short8 A = *(const short8*)(arow + (((kt*4 + kg) ^ rs) * 8));
                acc = __builtin_amdgcn_mfma_f32_16x16x32_bf16(A, W0h[kt], acc, 0, 0, 0);
                acc = __builtin_amdgcn_mfma_f32_16x16x32_bf16(A, W0l[kt], acc, 0, 0, 0);
            }
            if constexpr (STAGE == 0) {
#pragma unroll
                for (int r = 0; r < 4; ++r) {
                    float y = acc[r];
                    ssum[0] += y; ssq[0] += y * y;
                }
            } else {
#pragma unroll
                for (int r = 0; r < 4; ++r) {
                    int row = mt * 16 + kg * 4 + r;
                    float x1 = fmaxf(a0v * acc[r] + c0v, 0.f);
                    X1s[row * 64 + ((((chW >> 3) ^ (row & 7)) << 3) | (chW & 7))] = cvt_bf16(x1);
                }
            }
        }
        if constexpr (STAGE >= 1) {
            __syncthreads();           // X1 complete
            // ---- conv1: K=64 ----
#pragma unroll 2
            for (int mt = 0; mt < 8; ++mt) {
                const short* arow = X1s + (mt * 16 + ln) * 64;
                f32x4 acc = {bb1, bb1, bb1, bb1};
#pragma unroll
                for (int kt = 0; kt < 2; ++kt) {
                    short8 A = *(const short8*)(arow + (((kt*4 + kg) ^ rs) * 8));
                    acc = __builtin_amdgcn_mfma_f32_16x16x32_bf16(A, W1h[kt], acc, 0, 0, 0);
                    acc = __builtin_amdgcn_mfma_f32_16x16x32_bf16(A, W1l[kt], acc, 0, 0, 0);
                }
                if constexpr (STAGE == 1) {
#pragma unroll
                    for (int r = 0; r < 4; ++r) {
                        float y = acc[r];
                        ssum[0] += y; ssq[0] += y * y;
                    }
                } else {
#pragma unroll
                    for (int r = 0; r < 4; ++r) {
                        int row = mt * 16 + kg * 4 + r;
                        float x2 = fmaxf(a1v * acc[r] + c1v, 0.f);
                        Xs[row * 128 + ((((chW >> 3) ^ (row & 7)) << 3) | (chW & 7))] = cvt_bf16(x2);
                    }
                }
            }
        }
        if constexpr (STAGE == 2) {
            __syncthreads();           // X2 complete
            // ---- conv2: wave's 32 cols, 4 points, stats + max/min ----
#pragma unroll
            for (int p = 0; p < 4; ++p) {
                float mx0 = -3.402823466e38f, mn0 = 3.402823466e38f;
                float mx1 = -3.402823466e38f, mn1 = 3.402823466e38f;
#pragma unroll
                for (int mh = 0; mh < 2; ++mh) {
                    const int mt = p * 2 + mh;
                    const short* arow = Xs + (mt * 16 + ln) * 128;
                    short8 A0 = *(const short8*)(arow + (((kg)     ^ rs) * 8));
                    short8 A1 = *(const short8*)(arow + (((4 + kg) ^ rs) * 8));
                    f32x4 acc = {bb2a, bb2a, bb2a, bb2a};
                    acc = __builtin_amdgcn_mfma_f32_16x16x32_bf16(A0, W2h[0][0], acc, 0, 0, 0);
                    acc = __builtin_amdgcn_mfma_f32_16x16x32_bf16(A0, W2l[0][0], acc, 0, 0, 0);
                    acc = __builtin_amdgcn_mfma_f32_16x16x32_bf16(A1, W2h[0][1], acc, 0, 0, 0);
                    acc = __builtin_amdgcn_mfma_f32_16x16x32_bf16(A1, W2l[0][1], acc, 0, 0, 0);
#pragma unroll
                    for (int r = 0; r < 4; ++r) {
                        float y = acc[r];
                        ssum[0] += y; ssq[0] += y * y;
                        mx0 = fmaxf(mx0, y); mn0 = fminf(mn0, y);
                    }
                    f32x4 acd = {bb2b, bb2b, bb2b, bb2b};
                    acd = __builtin_amdgcn_mfma_f32_16x16x32_bf16(A0, W2h[1][0], acd, 0, 0, 0);
                    acd = __builtin_amdgcn_mfma_f32_16x16x32_bf16(A0, W2l[1][0], acd, 0, 0, 0);
                    acd = __builtin_amdgcn_mfma_f32_16x16x32_bf16(A1, W2h[1][1], acd, 0, 0, 0);
                    acd = __builtin_amdgcn_mfma_f32_16x16x32_bf16(A1, W2l[1][1], acd, 0, 0, 0);
#pragma unroll
                    for (int r = 0; r < 4; ++r) {
                        float y = acd[r];
                        ssum[1] += y; ssq[1] += y * y;
                        mx1 = fmaxf(mx1, y); mn1 = fminf(mn1, y);
                    }
                }
                mx0 = fmaxf(mx0, __shfl_xor(mx0, 16)); mn0 = fminf(mn0, __shfl_xor(mn0, 16));
                mx0 = fmaxf(mx0, __shfl_xor(mx0, 32)); mn0 = fminf(mn0, __shfl_xor(mn0, 32));
                mx1 = fmaxf(mx1, __shfl_xor(mx1, 16)); mn1 = fminf(mn1, __shfl_xor(mn1, 16));
                mx1 = fmaxf(mx1, __shfl_xor(mx1, 32)); mn1 = fminf(mn1, __shfl_xor(mn1, 32));
                if (lane < 16) {
                    size_t base = (size_t)(m0 + p) * 128 + wv * 32 + ln;
                    ymax[base]      = mx0; ymin[base]      = mn0;
                    ymax[base + 16] = mx1; ymin[base + 16] = mn1;
                }
            }
        }
    }

    // ---- stats epilogue: channels disjoint per wave -> direct write ----
    float* pb = part + (size_t)blockIdx.x * 256;
#pragma unroll
    for (int nt = 0; nt < NT; ++nt) {
        float v = ssum[nt], q = ssq[nt];
        v += __shfl_xor(v, 16); q += __shfl_xor(q, 16);
        v += __shfl_xor(v, 32); q += __shfl_xor(q, 32);
        if (lane < 16) {
            constexpr int NCH = (STAGE == 2) ? 128 : 64;
            int c = (STAGE == 2) ? (wv * 32 + nt * 16 + ln) : (wv * 16 + ln);
            pb[c] = v; pb[NCH + c] = q;
        }
    }
}

__global__ __launch_bounds__(256) void reduce_partials(
    const float* __restrict__ part, float* __restrict__ fstats,
    int base, int nblocks)
{
    __shared__ float red[256];
    int c = blockIdx.x;
    float s = 0.f;
    for (int b = threadIdx.x; b < nblocks; b += 256)
        s += part[(size_t)b * 256 + c];
    red[threadIdx.x] = s;
    __syncthreads();
    for (int off = 128; off > 0; off >>= 1) {
        if (threadIdx.x < off) red[threadIdx.x] += red[threadIdx.x + off];
        __syncthreads();
    }
    if (threadIdx.x == 0) fstats[base + c] = red[0];
}

__global__ __launch_bounds__(256) void final_kernel(
    const float* __restrict__ center, const float* __restrict__ normal,
    const int* __restrict__ offs,
    const float* __restrict__ g2, const float* __restrict__ be2,
    const float* __restrict__ fstats,
    const float* __restrict__ ymax, const float* __restrict__ ymin,
    float* __restrict__ out, int N, float inv_cnt)
{
    int i = blockIdx.x * 256 + threadIdx.x;
    int nc = N * 3;
    int nf = N * 128;
    int total = 2 * nc + nf + 1;
    if (i >= total) return;
    if (i < nc) {
        out[i] = center[i];
    } else if (i < 2 * nc) {
        out[i] = normal[i - nc];
    } else if (i < 2 * nc + nf) {
        int idx = i - 2 * nc;
        int c = idx & 127;
        float mean = fstats[256 + c] * inv_cnt;
        float var  = fstats[384 + c] * inv_cnt - mean * mean;
        float a = g2[c] * rsqrtf(fmaxf(var, 0.f) + BN_EPS);
        float v = (a >= 0.f) ? ymax[idx] : ymin[idx];   // monotone BN+relu
        out[i] = fmaxf(a * (v - mean) + be2[c], 0.f);
    } else {
        out[i] = (float)offs[0];
    }
}

extern "C" void kernel_launch(void* const* d_in, const int* in_sizes, int n_in,
                              void* d_out, int out_size, void* d_ws, size_t ws_size,
                              hipStream_t stream)
{
    const float* center  = (const float*)d_in[0];
    const float* normal  = (const float*)d_in[1];
    const float* feature = (const float*)d_in[2];
    const int*   offs    = (const int*)d_in[3];
    const int*   gidx    = (const int*)d_in[4];
    const float* w0  = (const float*)d_in[5];
    const float* b0  = (const float*)d_in[6];
    const float* g0  = (const float*)d_in[7];
    const float* be0 = (const float*)d_in[8];
    const float* w1  = (const float*)d_in[9];
    const float* b1  = (const float*)d_in[10];
    const float* g1  = (const float*)d_in[11];
    const float* be1 = (const float*)d_in[12];
    const float* w2  = (const float*)d_in[13];
    const float* b2  = (const float*)d_in[14];
    const float* g2  = (const float*)d_in[15];
    const float* be2 = (const float*)d_in[16];

    const int N = in_sizes[0] / 3;
    const int ntiles = N / 4;
    const float inv_cnt = 1.0f / (float)((size_t)N * NS);

    float* out = (float*)d_out;
    float* out_nf = out + (size_t)2 * N * 3;          // ymax in-place in d_out

    float* wsf    = (float*)d_ws;
    float* fstats = wsf;                              // [512]
    float* part   = wsf + 512;                        // [1024*256]
    float* ymin   = part + (size_t)1024 * 256;        // [N*128]
    short* wbase  = (short*)(ymin + (size_t)N * 128);
    short* wf0h = wbase;
    short* wf0l = wf0h + 12 * 512;
    short* wf1h = wf0l + 12 * 512;
    short* wf1l = wf1h + 8 * 512;
    short* wf2h = wf1l + 8 * 512;
    short* wf2l = wf2h + 16 * 512;
    short* wend = wf2l + 16 * 512;

    // gather tables
    short* featbf = wend;                             // [N*64] bf16
    float* cn     = (float*)(featbf + (size_t)N * 64);// [N*8] fp32
    size_t need = (size_t)((char*)(cn + (size_t)N * 8) - (char*)d_ws);
    const bool has_tab = (ws_size >= need);
    const short* fbp = has_tab ? featbf : nullptr;
    const float* cnp = has_tab ? cn : nullptr;

    dim3 blk(256);

    prep_weights<<<dim3(9), blk, 0, stream>>>(w0, w1, w2,
        wf0h, wf0l, wf1h, wf1l, wf2h, wf2l);
    if (has_tab) {
        int n8 = N * 8;
        feat2bf<<<dim3((n8 + 255) / 256), blk, 0, stream>>>(feature, featbf, n8);
        prep_cn<<<dim3((N + 255) / 256), blk, 0, stream>>>(center, normal, cn, N);
    }

    stage_kernel<0><<<dim3(GRID0), blk, 0, stream>>>(center, normal, feature,
        fbp, cnp, gidx, wf0h, wf0l, wf1h, wf1l, wf2h, wf2l, b0, b1, b2,
        g0, be0, g1, be1, fstats, part, out_nf, ymin, ntiles, inv_cnt);
    reduce_partials<<<dim3(128), blk, 0, stream>>>(part, fstats, 0, GRID0);

    stage_kernel<1><<<dim3(GRID12), blk, 0, stream>>>(center, normal, feature,
        fbp, cnp, gidx, wf0h, wf0l, wf1h, wf1l, wf2h, wf2l, b0, b1, b2,
        g0, be0, g1, be1, fstats, part, out_nf, ymin, ntiles, inv_cnt);
    reduce_partials<<<dim3(128), blk, 0, stream>>>(part, fstats, 128, GRID12);

    stage_kernel<2><<<dim3(GRID12), blk, 0, stream>>>(center, normal, feature,
        fbp, cnp, gidx, wf0h, wf0l, wf1h, wf1l, wf2h, wf2l, b0, b1, b2,
        g0, be0, g1, be1, fstats, part, out_nf, ymin, ntiles, inv_cnt);
    reduce_partials<<<dim3(256), blk, 0, stream>>>(part, fstats, 256, GRID12);

    int total = 2 * N * 3 + N * 128 + 1;
    final_kernel<<<dim3((total + 255) / 256), blk, 0, stream>>>(
        center, normal, offs, g2, be2, fstats, out_nf, ymin, out, N, inv_cnt);
}